// Round 1
// baseline (438.153 us; speedup 1.0000x reference)
//
#include <hip/hip_runtime.h>
#include <math.h>

// Dims fixed by the problem: x[64,512,1024] fp32, W[256,512] fp32,
// BN params [256] fp32, out[64,256] fp32 (spike rate over T=1024).
namespace {
constexpr int kB = 64, kCin = 512, kT = 1024, kCout = 256;
constexpr int kOTile = 32;    // outputs per block
constexpr int kTTile = 128;   // time steps per tile
constexpr int kCc = 64;       // channel chunk staged in LDS
constexpr int kNtt = kT / kTTile;   // 8 sequential time tiles (LIF carry)
constexpr int kNcc = kCin / kCc;    // 8 channel chunks
constexpr int kYPad = 132;          // ytile row stride (pad, 16B-aligned rows)
}

// Pre-transpose W[o][c] -> Wt[c][o] so the hot loop stages W coalesced and
// reads it from LDS as float4 along o. Tiny (512 KB), runs once per launch.
__global__ void wt_transpose_kernel(const float* __restrict__ W,
                                    float* __restrict__ Wt) {
    int idx = blockIdx.x * 256 + threadIdx.x;  // 0..131071
    int c = idx >> 8;        // Wt row
    int o = idx & 255;       // Wt col (contiguous -> coalesced store)
    Wt[idx] = W[o * kCin + c];
}

// Fused GEMM (fp32 vector FMA) + BatchNorm + LIF recurrence + spike-rate mean.
// Block = 256 threads: tx = tid&31 (4-t group), ty = tid>>5 (4-o group);
// each thread owns a 4o x 4t accumulator tile.
__global__ __launch_bounds__(256, 2)
void snn_fused_kernel(const float* __restrict__ x, const float* __restrict__ Wt,
                      const float* __restrict__ gamma, const float* __restrict__ beta,
                      const float* __restrict__ rmean, const float* __restrict__ rvar,
                      float* __restrict__ out) {
    __shared__ float xs[kCc][kTTile];        // 32 KB  x chunk [c][t]
    __shared__ float ws[kCc][kOTile];        // 8 KB   W chunk [c][o]
    __shared__ float ytile[kOTile][kYPad];   // 16.5 KB  y for LIF
    __shared__ float sarr[kOTile], barr[kOTile], marr[kOTile], vstate[kOTile];
    __shared__ int scnt[kOTile];

    const int tid = threadIdx.x;
    const int tx = tid & 31;
    const int ty = tid >> 5;
    const int b = blockIdx.y;
    const int o_blk = blockIdx.x * kOTile;

    if (tid < kOTile) {
        const int o = o_blk + tid;
        // inv = rsqrt(var+eps) computed in double to track the numpy reference
        const double dinv = 1.0 / sqrt((double)rvar[o] + 1e-5);
        sarr[tid] = (float)(dinv * (double)gamma[o]);
        barr[tid] = beta[o];
        marr[tid] = rmean[o];
        vstate[tid] = 0.0f;
        scnt[tid] = 0;
    }
    __syncthreads();

    const float* xb = x + (size_t)b * kCin * kT;

    for (int tt = 0; tt < kNtt; ++tt) {
        float acc[4][4];
#pragma unroll
        for (int i = 0; i < 4; ++i)
#pragma unroll
            for (int j = 0; j < 4; ++j) acc[i][j] = 0.0f;

        const int t0 = tt * kTTile;
        for (int cc = 0; cc < kNcc; ++cc) {
            // --- stage x chunk: kCc x kTTile floats, coalesced float4 loads ---
#pragma unroll
            for (int k = 0; k < 8; ++k) {
                const int f = tid + 256 * k;   // float4 index, 0..2047
                const int c = f >> 5;          // 32 float4 per row
                const int tq = f & 31;
                const float4 v4 = *reinterpret_cast<const float4*>(
                    xb + (size_t)(cc * kCc + c) * kT + t0 + tq * 4);
                *reinterpret_cast<float4*>(&xs[c][tq * 4]) = v4;
            }
            // --- stage W chunk: kCc x kOTile floats (Wt is [c][o], coalesced) ---
#pragma unroll
            for (int k = 0; k < 2; ++k) {
                const int f = tid + 256 * k;   // float4 index, 0..511
                const int c = f >> 3;          // 8 float4 per row
                const int oq = f & 7;
                const float4 v4 = *reinterpret_cast<const float4*>(
                    Wt + (size_t)(cc * kCc + c) * kCout + o_blk + oq * 4);
                *reinterpret_cast<float4*>(&ws[c][oq * 4]) = v4;
            }
            __syncthreads();

            // --- inner product: 16 FMA per 2 ds_read_b128 ---
#pragma unroll 8
            for (int c = 0; c < kCc; ++c) {
                const float4 xv = *reinterpret_cast<const float4*>(&xs[c][tx * 4]);
                const float4 wv = *reinterpret_cast<const float4*>(&ws[c][ty * 4]);
                const float xf[4] = {xv.x, xv.y, xv.z, xv.w};
                const float wf[4] = {wv.x, wv.y, wv.z, wv.w};
#pragma unroll
                for (int i = 0; i < 4; ++i)
#pragma unroll
                    for (int j = 0; j < 4; ++j) acc[i][j] += wf[i] * xf[j];
            }
            __syncthreads();
        }

        // --- BatchNorm affine, write y tile to LDS ---
#pragma unroll
        for (int i = 0; i < 4; ++i) {
            const int o = ty * 4 + i;
            const float s = sarr[o], bb = barr[o], m = marr[o];
#pragma unroll
            for (int j = 0; j < 4; ++j) {
                ytile[o][tx * 4 + j] = (acc[i][j] - m) * s + bb;
            }
        }
        __syncthreads();

        // --- LIF recurrence over this time tile: one lane per output channel ---
        if (tid < kOTile) {
            float vv = vstate[tid];
            int cnt = 0;
#pragma unroll 4
            for (int t = 0; t < kTTile; ++t) {
                const float y = ytile[tid][t];
                vv = vv + (y - vv) * 0.5f;            // v += (y - v)/TAU, TAU=2
                if (vv - 1.0f >= 0.0f) { cnt++; vv = 0.0f; }  // spike + hard reset
            }
            vstate[tid] = vv;
            scnt[tid] += cnt;
        }
        __syncthreads();
    }

    if (tid < kOTile) {
        out[b * kCout + o_blk + tid] = (float)scnt[tid] * (1.0f / 1024.0f);
    }
}

extern "C" void kernel_launch(void* const* d_in, const int* in_sizes, int n_in,
                              void* d_out, int out_size, void* d_ws, size_t ws_size,
                              hipStream_t stream) {
    const float* x     = (const float*)d_in[0];
    const float* W     = (const float*)d_in[1];
    const float* gamma = (const float*)d_in[2];
    const float* beta  = (const float*)d_in[3];
    const float* rmean = (const float*)d_in[4];
    const float* rvar  = (const float*)d_in[5];
    float* out = (float*)d_out;
    float* Wt = (float*)d_ws;  // 512 KB scratch for transposed W

    wt_transpose_kernel<<<(kCin * kCout) / 256, 256, 0, stream>>>(W, Wt);
    snn_fused_kernel<<<dim3(kCout / kOTile, kB), 256, 0, stream>>>(
        x, Wt, gamma, beta, rmean, rvar, out);
}

// Round 2
// 283.845 us; speedup vs baseline: 1.5436x; 1.5436x over previous
//
#include <hip/hip_runtime.h>
#include <math.h>

typedef __attribute__((ext_vector_type(8)))  __bf16 bf16v8;
typedef __attribute__((ext_vector_type(16))) float  f32x16;
typedef __attribute__((ext_vector_type(4)))  float  f32x4;

namespace {
constexpr int kB = 64, kCin = 512, kT = 1024, kCout = 256;
constexpr size_t kYBytes    = (size_t)kB * kT * kCout * 4;   // 64 MiB y buffer
constexpr size_t kWfragBytes = (size_t)32 * 8 * 3 * 64 * 16; // 786432: [kc][osub][plane][lane][16B]
constexpr size_t kSBytes    = kCout * 4;
constexpr size_t kWsNeed    = kYBytes + kWfragBytes + kSBytes;
}

// ---------------- prep: split W into 3 bf16 planes, stored in A-frag lane order ----
// Layout: idx = ((kc*8 + osub)*3 + p)*64 + lane, 8 bf16 per entry.
// A-frag assumption (32x32x16_bf16): m = lane&31, k = (lane>>5)*8 + j.
__global__ void wsplit_kernel(const float* __restrict__ W, __bf16* __restrict__ wfrag) {
    const int kc = blockIdx.x, osub = blockIdx.y, p = blockIdx.z;
    const int lane = threadIdx.x;
    const int o  = osub * 32 + (lane & 31);
    const int kb = kc * 16 + (lane >> 5) * 8;
    bf16v8 frag;
#pragma unroll
    for (int j = 0; j < 8; ++j) {
        const float w = W[o * kCin + kb + j];
        const __bf16 h = (__bf16)w;           // RNE
        const float r1 = w - (float)h;        // exact
        const __bf16 m = (__bf16)r1;
        const float r2 = r1 - (float)m;       // exact
        const __bf16 l = (__bf16)r2;
        frag[j] = (p == 0) ? h : (p == 1) ? m : l;
    }
    const size_t idx = ((size_t)(kc * 8 + osub) * 3 + p) * 64 + lane;
    *reinterpret_cast<bf16v8*>(wfrag + idx * 8) = frag;
}

__global__ void sprep_kernel(const float* __restrict__ gamma, const float* __restrict__ rvar,
                             float* __restrict__ sarr) {
    const int o = threadIdx.x;
    sarr[o] = (float)((double)gamma[o] / sqrt((double)rvar[o] + 1e-5));
}

// ---------------- GEMM: split-bf16 MFMA, no barriers in K-loop ----------------
// Grid (8 t-chunks, 64 b), 512 threads = 8 waves. Block tile 256o x 128t,
// wave tile 64o x 64t = 2x2 MFMA 32x32 tiles. y written as [b][t][o].
__global__ __launch_bounds__(512, 2)
void gemm_split_kernel(const float* __restrict__ x, const __bf16* __restrict__ wfrag,
                       const float* __restrict__ sarr, const float* __restrict__ rmean,
                       const float* __restrict__ beta, float* __restrict__ y) {
    __shared__ float tbuf[8 * 32 * 36];   // per-wave 32x32 transpose buffer (stride 36)
    const int tid  = threadIdx.x;
    const int lane = tid & 63;
    const int wave = tid >> 6;
    const int wo = wave >> 1, wt = wave & 1;
    const int n = lane & 31, q = lane >> 5;
    const int b  = blockIdx.y;
    const int o0 = wo * 64;
    const int t0 = blockIdx.x * 128 + wt * 64;
    const float* __restrict__ xb = x + ((size_t)b << 19);   // b*512*1024
    const bf16v8* __restrict__ wf = reinterpret_cast<const bf16v8*>(wfrag);

    f32x16 acc[2][2] = {};

    float  xr[2][2][8];    // [buf][t-sub][j]  fp32 B-frag staging
    bf16v8 ar[2][2][3];    // [buf][o-sub][plane] A frags

    auto loadk = [&](int kc, float (&xd)[2][8], bf16v8 (&ad)[2][3]) {
#pragma unroll
        for (int s = 0; s < 2; ++s)
#pragma unroll
            for (int j = 0; j < 8; ++j)
                xd[s][j] = xb[(size_t)(kc * 16 + q * 8 + j) * kT + t0 + s * 32 + n];
#pragma unroll
        for (int i = 0; i < 2; ++i)
#pragma unroll
            for (int p = 0; p < 3; ++p)
                ad[i][p] = wf[(size_t)((kc * 8 + wo * 2 + i) * 3 + p) * 64 + lane];
    };

    auto compute = [&](const float (&xd)[2][8], const bf16v8 (&ad)[2][3]) {
        bf16v8 Bh[2], Bm[2], Bl[2];
#pragma unroll
        for (int s = 0; s < 2; ++s) {
#pragma unroll
            for (int j = 0; j < 8; ++j) {
                const float f = xd[s][j];
                const __bf16 h = (__bf16)f;
                const float r1 = f - (float)h;
                const __bf16 m = (__bf16)r1;
                const float r2 = r1 - (float)m;
                const __bf16 l = (__bf16)r2;
                Bh[s][j] = h; Bm[s][j] = m; Bl[s][j] = l;
            }
        }
#pragma unroll
        for (int i = 0; i < 2; ++i)
#pragma unroll
            for (int s = 0; s < 2; ++s) {
                f32x16 a = acc[i][s];
                a = __builtin_amdgcn_mfma_f32_32x32x16_bf16(ad[i][0], Bh[s], a, 0, 0, 0); // hh
                a = __builtin_amdgcn_mfma_f32_32x32x16_bf16(ad[i][0], Bm[s], a, 0, 0, 0); // hm
                a = __builtin_amdgcn_mfma_f32_32x32x16_bf16(ad[i][1], Bh[s], a, 0, 0, 0); // mh
                a = __builtin_amdgcn_mfma_f32_32x32x16_bf16(ad[i][0], Bl[s], a, 0, 0, 0); // hl
                a = __builtin_amdgcn_mfma_f32_32x32x16_bf16(ad[i][2], Bh[s], a, 0, 0, 0); // lh
                a = __builtin_amdgcn_mfma_f32_32x32x16_bf16(ad[i][1], Bm[s], a, 0, 0, 0); // mm
                acc[i][s] = a;
            }
    };

    loadk(0, xr[0], ar[0]);
    for (int kc2 = 0; kc2 < 16; ++kc2) {
        loadk(2 * kc2 + 1, xr[1], ar[1]);
        compute(xr[0], ar[0]);
        if (kc2 < 15) loadk(2 * kc2 + 2, xr[0], ar[0]);
        compute(xr[1], ar[1]);
    }

    // ---- epilogue: per-wave LDS transpose (o-major frag -> t-major rows) + BN ----
    float* tb = tbuf + wave * (32 * 36);
#pragma unroll
    for (int i = 0; i < 2; ++i)
#pragma unroll
        for (int s = 0; s < 2; ++s) {
            asm volatile("s_waitcnt lgkmcnt(0)" ::: "memory");
#pragma unroll
            for (int g = 0; g < 4; ++g) {
                f32x4 v;
                v.x = acc[i][s][4 * g + 0];
                v.y = acc[i][s][4 * g + 1];
                v.z = acc[i][s][4 * g + 2];
                v.w = acc[i][s][4 * g + 3];
                // C/D: col(t) = lane&31, row(o) = (reg&3) + 8*(reg>>2) + 4*(lane>>5)
                *reinterpret_cast<f32x4*>(tb + n * 36 + g * 8 + q * 4) = v;
            }
            asm volatile("s_waitcnt lgkmcnt(0)" ::: "memory");
#pragma unroll
            for (int r4 = 0; r4 < 4; ++r4) {
                const int fidx = lane + 64 * r4;
                const int tl = fidx >> 3, o4 = fidx & 7;
                const int og = o0 + i * 32 + o4 * 4;
                f32x4 val = *reinterpret_cast<const f32x4*>(tb + tl * 36 + o4 * 4);
                const f32x4 sv = *reinterpret_cast<const f32x4*>(sarr + og);
                const f32x4 mv = *reinterpret_cast<const f32x4*>(rmean + og);
                const f32x4 bv = *reinterpret_cast<const f32x4*>(beta + og);
                val = (val - mv) * sv + bv;   // same form as round-1 (absmax 0)
                const size_t t = (size_t)t0 + s * 32 + tl;
                *reinterpret_cast<f32x4*>(y + ((((size_t)b << 10) + t) << 8) + og) = val;
            }
        }
}

// ---------------- LIF: one wave per (b, 64-o slice), deep load pipelining ------
__global__ __launch_bounds__(64)
void lif_kernel(const float* __restrict__ y, float* __restrict__ out) {
    const int b = blockIdx.x >> 2;
    const int o = ((blockIdx.x & 3) << 6) + threadIdx.x;
    const float* __restrict__ yb = y + ((size_t)b << 18);
    float v = 0.f;
    int cnt = 0;
    float b0[32], b1[32];
    auto loadb = [&](int i, float (&buf)[32]) {
#pragma unroll
        for (int j = 0; j < 32; ++j)
            buf[j] = yb[(size_t)(i * 32 + j) * 256 + o];
    };
    auto stepb = [&](const float (&buf)[32]) {
#pragma unroll
        for (int j = 0; j < 32; ++j) {
            v = v + (buf[j] - v) * 0.5f;
            if (v - 1.0f >= 0.0f) { ++cnt; v = 0.f; }
        }
    };
    loadb(0, b0);
    for (int bb = 0; bb < 16; ++bb) {
        loadb(2 * bb + 1, b1);
        stepb(b0);
        if (bb < 15) loadb(2 * bb + 2, b0);
        stepb(b1);
    }
    out[((size_t)b << 8) + o] = (float)cnt * (1.0f / 1024.0f);
}

// ---------------- fallback (round-1 fp32 fused path) ---------------------------
namespace fb {
constexpr int kOTile = 32, kTTile = 128, kCc = 64;
constexpr int kNtt = kT / kTTile, kNcc = kCin / kCc, kYPad = 132;
}

__global__ void wt_transpose_kernel(const float* __restrict__ W, float* __restrict__ Wt) {
    int idx = blockIdx.x * 256 + threadIdx.x;
    int c = idx >> 8, o = idx & 255;
    Wt[idx] = W[o * kCin + c];
}

__global__ __launch_bounds__(256, 2)
void snn_fused_kernel(const float* __restrict__ x, const float* __restrict__ Wt,
                      const float* __restrict__ gamma, const float* __restrict__ beta,
                      const float* __restrict__ rmean, const float* __restrict__ rvar,
                      float* __restrict__ out) {
    using namespace fb;
    __shared__ float xs[kCc][kTTile];
    __shared__ float ws[kCc][kOTile];
    __shared__ float ytile[kOTile][kYPad];
    __shared__ float sarr[kOTile], barr[kOTile], marr[kOTile], vstate[kOTile];
    __shared__ int scnt[kOTile];
    const int tid = threadIdx.x, tx = tid & 31, ty = tid >> 5;
    const int b = blockIdx.y, o_blk = blockIdx.x * kOTile;
    if (tid < kOTile) {
        const int o = o_blk + tid;
        const double dinv = 1.0 / sqrt((double)rvar[o] + 1e-5);
        sarr[tid] = (float)(dinv * (double)gamma[o]);
        barr[tid] = beta[o]; marr[tid] = rmean[o];
        vstate[tid] = 0.0f; scnt[tid] = 0;
    }
    __syncthreads();
    const float* xb = x + (size_t)b * kCin * kT;
    for (int tt = 0; tt < kNtt; ++tt) {
        float acc[4][4];
#pragma unroll
        for (int i = 0; i < 4; ++i)
#pragma unroll
            for (int j = 0; j < 4; ++j) acc[i][j] = 0.0f;
        const int t0 = tt * kTTile;
        for (int cc = 0; cc < kNcc; ++cc) {
#pragma unroll
            for (int k = 0; k < 8; ++k) {
                const int f = tid + 256 * k;
                const int c = f >> 5, tq = f & 31;
                *reinterpret_cast<float4*>(&xs[c][tq * 4]) = *reinterpret_cast<const float4*>(
                    xb + (size_t)(cc * kCc + c) * kT + t0 + tq * 4);
            }
#pragma unroll
            for (int k = 0; k < 2; ++k) {
                const int f = tid + 256 * k;
                const int c = f >> 3, oq = f & 7;
                *reinterpret_cast<float4*>(&ws[c][oq * 4]) = *reinterpret_cast<const float4*>(
                    Wt + (size_t)(cc * kCc + c) * kCout + o_blk + oq * 4);
            }
            __syncthreads();
#pragma unroll 8
            for (int c = 0; c < kCc; ++c) {
                const float4 xv = *reinterpret_cast<const float4*>(&xs[c][tx * 4]);
                const float4 wv = *reinterpret_cast<const float4*>(&ws[c][ty * 4]);
                const float xf[4] = {xv.x, xv.y, xv.z, xv.w};
                const float wf4[4] = {wv.x, wv.y, wv.z, wv.w};
#pragma unroll
                for (int i = 0; i < 4; ++i)
#pragma unroll
                    for (int j = 0; j < 4; ++j) acc[i][j] += wf4[i] * xf[j];
            }
            __syncthreads();
        }
#pragma unroll
        for (int i = 0; i < 4; ++i) {
            const int o = ty * 4 + i;
            const float s = sarr[o], bb2 = barr[o], m = marr[o];
#pragma unroll
            for (int j = 0; j < 4; ++j) ytile[o][tx * 4 + j] = (acc[i][j] - m) * s + bb2;
        }
        __syncthreads();
        if (tid < kOTile) {
            float vv = vstate[tid];
            int cnt = 0;
#pragma unroll 4
            for (int t = 0; t < kTTile; ++t) {
                const float yv = ytile[tid][t];
                vv = vv + (yv - vv) * 0.5f;
                if (vv - 1.0f >= 0.0f) { cnt++; vv = 0.0f; }
            }
            vstate[tid] = vv; scnt[tid] += cnt;
        }
        __syncthreads();
    }
    if (tid < kOTile) out[b * kCout + o_blk + tid] = (float)scnt[tid] * (1.0f / 1024.0f);
}

extern "C" void kernel_launch(void* const* d_in, const int* in_sizes, int n_in,
                              void* d_out, int out_size, void* d_ws, size_t ws_size,
                              hipStream_t stream) {
    const float* x     = (const float*)d_in[0];
    const float* W     = (const float*)d_in[1];
    const float* gamma = (const float*)d_in[2];
    const float* beta  = (const float*)d_in[3];
    const float* rmean = (const float*)d_in[4];
    const float* rvar  = (const float*)d_in[5];
    float* out = (float*)d_out;

    if (ws_size >= kWsNeed) {
        float*  y     = (float*)d_ws;
        __bf16* wfrag = (__bf16*)((char*)d_ws + kYBytes);
        float*  sarr  = (float*)((char*)d_ws + kYBytes + kWfragBytes);
        sprep_kernel<<<1, 256, 0, stream>>>(gamma, rvar, sarr);
        wsplit_kernel<<<dim3(32, 8, 3), 64, 0, stream>>>(W, wfrag);
        gemm_split_kernel<<<dim3(8, 64), 512, 0, stream>>>(x, wfrag, sarr, rmean, beta, y);
        lif_kernel<<<256, 64, 0, stream>>>(y, out);
    } else {
        float* Wt = (float*)d_ws;
        wt_transpose_kernel<<<(kCin * kCout) / 256, 256, 0, stream>>>(W, Wt);
        snn_fused_kernel<<<dim3(kCout / fb::kOTile, kB), 256, 0, stream>>>(
            x, Wt, gamma, beta, rmean, rvar, out);
    }
}

// Round 4
// 263.901 us; speedup vs baseline: 1.6603x; 1.0756x over previous
//
#include <hip/hip_runtime.h>
#include <math.h>

typedef _Float16 f16;
typedef __attribute__((ext_vector_type(8)))  _Float16 f16v8;
typedef __attribute__((ext_vector_type(16))) float    f32x16;
typedef __attribute__((ext_vector_type(4)))  float    f32x4;

namespace {
constexpr int kB = 64, kCin = 512, kT = 1024, kCout = 256;
constexpr size_t kYBytes     = (size_t)kB * kT * kCout * 4;    // 64 MiB y buffer
constexpr size_t kWfragBytes = (size_t)32 * 8 * 2 * 64 * 16;   // 512 KiB [kc][osub][plane][lane][16B]
constexpr size_t kSBytes     = kCout * 4;
constexpr size_t kWsNeed     = kYBytes + kWfragBytes + kSBytes;
}

// ---- prep: W' = 32*W split into 2 f16 planes (low plane scaled 2^11), A-frag order ----
// A-frag (32x32x16): m(o) = lane&31, k = (lane>>5)*8 + j.
__global__ void wsplit16_kernel(const float* __restrict__ W, f16* __restrict__ wfrag) {
    const int kc = blockIdx.x, osub = blockIdx.y, p = blockIdx.z;
    const int lane = threadIdx.x;
    const int o  = osub * 32 + (lane & 31);
    const int kb = kc * 16 + (lane >> 5) * 8;
    f16v8 frag;
#pragma unroll
    for (int j = 0; j < 8; ++j) {
        const float w = 32.0f * W[o * kCin + kb + j];   // 2^5 pre-scale (denorm guard)
        const f16 h = (f16)w;                           // RNE
        const float r = w - (float)h;                   // exact
        const f16 l = (f16)(r * 2048.0f);               // low plane scaled 2^11
        frag[j] = p ? l : h;
    }
    *reinterpret_cast<f16v8*>(wfrag + ((size_t)((kc * 8 + osub) * 2 + p) * 64 + lane) * 8) = frag;
}

__global__ void sprep_kernel(const float* __restrict__ gamma, const float* __restrict__ rvar,
                             float* __restrict__ sarr) {
    const int o = threadIdx.x;
    sarr[o] = (float)((double)gamma[o] / sqrt((double)rvar[o] + 1e-5));
}

// ---- GEMM: f16 2-plane MFMA, LDS-shared B split, double-buffered, 1 barrier/chunk ----
// Grid (16 t-chunks, 64 b), 512 threads = 8 waves. Block tile 256o x 64t.
// Waves: wo = wave>>1 (4 o-groups of 64), wt = wave&1 (2 t-groups of 32).
// Wave tile 64o x 32t = 2 MFMA o-subs, dual accumulators (hh / cross).
__global__ __launch_bounds__(512, 2)
void gemm_f16_kernel(const float* __restrict__ x, const f16* __restrict__ wfrag,
                     const float* __restrict__ sarr, const float* __restrict__ rmean,
                     const float* __restrict__ beta, float* __restrict__ y) {
    __shared__ union {
        f16   B[2][2][64 * 24];   // [buf][plane][t*24 + swizzled k], 12 KiB
        float tb[8][32 * 36];     // per-wave epilogue transpose, 36 KiB
    } sh;

    const int tid  = threadIdx.x;
    const int lane = tid & 63;
    const int wave = tid >> 6;
    const int wo = wave >> 1, wt = wave & 1;
    const int n = lane & 31, q = lane >> 5;
    const int b   = blockIdx.y;
    const int tg0 = blockIdx.x * 64;
    const int o0  = wo * 64;
    const float* __restrict__ xb = x + ((size_t)b << 19);   // b*512*1024
    const f16v8* __restrict__ wf = reinterpret_cast<const f16v8*>(wfrag);

    // staging role: st_t = lane (t within tile), st_k = wave (k-pair index 0..7)
    const int st_t = lane;
    const int st_k = wave;
    const int wrow = st_t * 24 + 2 * (st_k ^ ((st_t >> 3 & 1) << 2));  // XOR swizzle
    const int tloc = wt * 32 + n;
    const int rrow = tloc * 24 + 8 * (q ^ (tloc >> 3 & 1));

    f32x16 accA[2] = {};
    f32x16 accB[2] = {};
    f16v8  af[2][2][2];   // [buf][osub][plane]
    float  x0a, x1a;

    auto loadX = [&](int kc) {
        const float* px = xb + (size_t)(kc * 16 + 2 * st_k) * kT + tg0 + st_t;
        x0a = px[0];
        x1a = px[kT];
    };
    auto loadA = [&](int kc, f16v8 (&ad)[2][2]) {
#pragma unroll
        for (int i = 0; i < 2; ++i)
#pragma unroll
            for (int p = 0; p < 2; ++p)
                ad[i][p] = wf[(size_t)((kc * 8 + wo * 2 + i) * 2 + p) * 64 + lane];
    };
    auto stage = [&](int buf) {
        auto h2 = __builtin_amdgcn_cvt_pkrtz(x0a, x1a);   // __fp16 x2, RTZ pack (k, k+1)
        const float r0 = x0a - (float)h2[0];              // exact (Sterbenz)
        const float r1 = x1a - (float)h2[1];
        auto l2 = __builtin_amdgcn_cvt_pkrtz(r0 * 2048.0f, r1 * 2048.0f);
        *reinterpret_cast<decltype(h2)*>(&sh.B[buf][0][wrow]) = h2;
        *reinterpret_cast<decltype(l2)*>(&sh.B[buf][1][wrow]) = l2;
    };
    auto domfma = [&](int buf, const f16v8 (&ad)[2][2]) {
        const f16v8 bh = *reinterpret_cast<const f16v8*>(&sh.B[buf][0][rrow]);
        const f16v8 bl = *reinterpret_cast<const f16v8*>(&sh.B[buf][1][rrow]);
#pragma unroll
        for (int i = 0; i < 2; ++i) {
            accA[i] = __builtin_amdgcn_mfma_f32_32x32x16_f16(ad[i][0], bh, accA[i], 0, 0, 0); // hh
            accB[i] = __builtin_amdgcn_mfma_f32_32x32x16_f16(ad[i][0], bl, accB[i], 0, 0, 0); // hl
            accB[i] = __builtin_amdgcn_mfma_f32_32x32x16_f16(ad[i][1], bh, accB[i], 0, 0, 0); // lh
        }
    };

    // prologue: stage chunk 0, prefetch chunk-1 x and chunk-0 A
    loadX(0);
    loadA(0, af[0]);
    stage(0);
    loadX(1);
    __syncthreads();

#pragma unroll 2
    for (int kc = 0; kc < 32; ++kc) {
        const int cur = kc & 1, nxt = cur ^ 1;
        if (kc < 31) loadA(kc + 1, af[nxt]);
        if (kc < 31) stage(nxt);          // consumes x of chunk kc+1
        if (kc < 30) loadX(kc + 2);       // refill register staging
        domfma(cur, af[cur]);
        __syncthreads();
    }

    // ---- epilogue: combine planes, per-wave LDS transpose, BN affine, store y[b][t][o] ----
    float* tb = sh.tb[wave];
#pragma unroll
    for (int i = 0; i < 2; ++i) {
        const f32x16 v = accA[i] + accB[i] * 4.8828125e-4f;   // + cross/2^11
        asm volatile("s_waitcnt lgkmcnt(0)" ::: "memory");
#pragma unroll
        for (int g = 0; g < 4; ++g) {
            f32x4 t4;
            t4.x = v[4 * g + 0]; t4.y = v[4 * g + 1];
            t4.z = v[4 * g + 2]; t4.w = v[4 * g + 3];
            // C/D: col(t)=lane&31, row(o)=(reg&3)+8*(reg>>2)+4*(lane>>5)
            *reinterpret_cast<f32x4*>(tb + n * 36 + g * 8 + q * 4) = t4;
        }
        asm volatile("s_waitcnt lgkmcnt(0)" ::: "memory");
#pragma unroll
        for (int r4 = 0; r4 < 4; ++r4) {
            const int fidx = lane + 64 * r4;
            const int tl = fidx >> 3, o4 = fidx & 7;
            const int og = o0 + i * 32 + o4 * 4;
            f32x4 val = *reinterpret_cast<const f32x4*>(tb + tl * 36 + o4 * 4);
            const f32x4 sv = *reinterpret_cast<const f32x4*>(sarr + og);
            const f32x4 mv = *reinterpret_cast<const f32x4*>(rmean + og);
            const f32x4 bv = *reinterpret_cast<const f32x4*>(beta + og);
            val = (val * 0.03125f - mv) * sv + bv;   // exact /32 un-scale, then BN
            const size_t t = (size_t)tg0 + wt * 32 + tl;
            *reinterpret_cast<f32x4*>(y + ((((size_t)b << 10) + t) << 8) + og) = val;
        }
    }
}

// ---- LIF: one wave per (b, 64-o slice), deep load pipelining ----
__global__ __launch_bounds__(64)
void lif_kernel(const float* __restrict__ y, float* __restrict__ out) {
    const int b = blockIdx.x >> 2;
    const int o = ((blockIdx.x & 3) << 6) + threadIdx.x;
    const float* __restrict__ yb = y + ((size_t)b << 18);
    float v = 0.f;
    int cnt = 0;
    float b0[32], b1[32];
    auto loadb = [&](int i, float (&buf)[32]) {
#pragma unroll
        for (int j = 0; j < 32; ++j)
            buf[j] = yb[(size_t)(i * 32 + j) * 256 + o];
    };
    auto stepb = [&](const float (&buf)[32]) {
#pragma unroll
        for (int j = 0; j < 32; ++j) {
            v = v + (buf[j] - v) * 0.5f;
            if (v - 1.0f >= 0.0f) { ++cnt; v = 0.f; }
        }
    };
    loadb(0, b0);
    for (int bb = 0; bb < 16; ++bb) {
        loadb(2 * bb + 1, b1);
        stepb(b0);
        if (bb < 15) loadb(2 * bb + 2, b0);
        stepb(b1);
    }
    out[((size_t)b << 8) + o] = (float)cnt * (1.0f / 1024.0f);
}

// ---- fallback (round-1 fp32 fused path, unchanged) ----
namespace fb {
constexpr int kOTile = 32, kTTile = 128, kCc = 64;
constexpr int kNtt = kT / kTTile, kNcc = kCin / kCc, kYPad = 132;
}

__global__ void wt_transpose_kernel(const float* __restrict__ W, float* __restrict__ Wt) {
    int idx = blockIdx.x * 256 + threadIdx.x;
    int c = idx >> 8, o = idx & 255;
    Wt[idx] = W[o * kCin + c];
}

__global__ __launch_bounds__(256, 2)
void snn_fused_kernel(const float* __restrict__ x, const float* __restrict__ Wt,
                      const float* __restrict__ gamma, const float* __restrict__ beta,
                      const float* __restrict__ rmean, const float* __restrict__ rvar,
                      float* __restrict__ out) {
    using namespace fb;
    __shared__ float xs[kCc][kTTile];
    __shared__ float ws[kCc][kOTile];
    __shared__ float ytile[kOTile][kYPad];
    __shared__ float sarr[kOTile], barr[kOTile], marr[kOTile], vstate[kOTile];
    __shared__ int scnt[kOTile];
    const int tid = threadIdx.x, tx = tid & 31, ty = tid >> 5;
    const int b = blockIdx.y, o_blk = blockIdx.x * kOTile;
    if (tid < kOTile) {
        const int o = o_blk + tid;
        const double dinv = 1.0 / sqrt((double)rvar[o] + 1e-5);
        sarr[tid] = (float)(dinv * (double)gamma[o]);
        barr[tid] = beta[o]; marr[tid] = rmean[o];
        vstate[tid] = 0.0f; scnt[tid] = 0;
    }
    __syncthreads();
    const float* xb = x + (size_t)b * kCin * kT;
    for (int tt = 0; tt < kNtt; ++tt) {
        float acc[4][4];
#pragma unroll
        for (int i = 0; i < 4; ++i)
#pragma unroll
            for (int j = 0; j < 4; ++j) acc[i][j] = 0.0f;
        const int t0 = tt * kTTile;
        for (int cc = 0; cc < kNcc; ++cc) {
#pragma unroll
            for (int k = 0; k < 8; ++k) {
                const int f = tid + 256 * k;
                const int c = f >> 5, tq = f & 31;
                *reinterpret_cast<float4*>(&xs[c][tq * 4]) = *reinterpret_cast<const float4*>(
                    xb + (size_t)(cc * kCc + c) * kT + t0 + tq * 4);
            }
#pragma unroll
            for (int k = 0; k < 2; ++k) {
                const int f = tid + 256 * k;
                const int c = f >> 3, oq = f & 7;
                *reinterpret_cast<float4*>(&ws[c][oq * 4]) = *reinterpret_cast<const float4*>(
                    Wt + (size_t)(cc * kCc + c) * kCout + o_blk + oq * 4);
            }
            __syncthreads();
#pragma unroll 8
            for (int c = 0; c < kCc; ++c) {
                const float4 xv = *reinterpret_cast<const float4*>(&xs[c][tx * 4]);
                const float4 wv = *reinterpret_cast<const float4*>(&ws[c][ty * 4]);
                const float xf[4] = {xv.x, xv.y, xv.z, xv.w};
                const float wf4[4] = {wv.x, wv.y, wv.z, wv.w};
#pragma unroll
                for (int i = 0; i < 4; ++i)
#pragma unroll
                    for (int j = 0; j < 4; ++j) acc[i][j] += wf4[i] * xf[j];
            }
            __syncthreads();
        }
#pragma unroll
        for (int i = 0; i < 4; ++i) {
            const int o = ty * 4 + i;
            const float s = sarr[o], bb2 = barr[o], m = marr[o];
#pragma unroll
            for (int j = 0; j < 4; ++j) ytile[o][tx * 4 + j] = (acc[i][j] - m) * s + bb2;
        }
        __syncthreads();
        if (tid < kOTile) {
            float vv = vstate[tid];
            int cnt = 0;
#pragma unroll 4
            for (int t = 0; t < kTTile; ++t) {
                const float yv = ytile[tid][t];
                vv = vv + (yv - vv) * 0.5f;
                if (vv - 1.0f >= 0.0f) { cnt++; vv = 0.0f; }
            }
            vstate[tid] = vv; scnt[tid] += cnt;
        }
        __syncthreads();
    }
    if (tid < kOTile) out[b * kCout + o_blk + tid] = (float)scnt[tid] * (1.0f / 1024.0f);
}

extern "C" void kernel_launch(void* const* d_in, const int* in_sizes, int n_in,
                              void* d_out, int out_size, void* d_ws, size_t ws_size,
                              hipStream_t stream) {
    const float* x     = (const float*)d_in[0];
    const float* W     = (const float*)d_in[1];
    const float* gamma = (const float*)d_in[2];
    const float* beta  = (const float*)d_in[3];
    const float* rmean = (const float*)d_in[4];
    const float* rvar  = (const float*)d_in[5];
    float* out = (float*)d_out;

    if (ws_size >= kWsNeed) {
        float* y     = (float*)d_ws;
        f16*   wfrag = (f16*)((char*)d_ws + kYBytes);
        float* sarr  = (float*)((char*)d_ws + kYBytes + kWfragBytes);
        sprep_kernel<<<1, 256, 0, stream>>>(gamma, rvar, sarr);
        wsplit16_kernel<<<dim3(32, 8, 2), 64, 0, stream>>>(W, wfrag);
        gemm_f16_kernel<<<dim3(16, 64), 512, 0, stream>>>(x, wfrag, sarr, rmean, beta, y);
        lif_kernel<<<256, 64, 0, stream>>>(y, out);
    } else {
        float* Wt = (float*)d_ws;
        wt_transpose_kernel<<<(kCin * kCout) / 256, 256, 0, stream>>>(W, Wt);
        snn_fused_kernel<<<dim3(kCout / fb::kOTile, kB), 256, 0, stream>>>(
            x, Wt, gamma, beta, rmean, rvar, out);
    }
}

// Round 5
// 256.217 us; speedup vs baseline: 1.7101x; 1.0300x over previous
//
#include <hip/hip_runtime.h>
#include <math.h>

typedef _Float16 f16;
typedef __attribute__((ext_vector_type(8)))  _Float16 f16v8;
typedef __attribute__((ext_vector_type(4)))  __fp16   h16v4;
typedef __attribute__((ext_vector_type(16))) float    f32x16;
typedef __attribute__((ext_vector_type(4)))  float    f32x4;

namespace {
constexpr int kB = 64, kCin = 512, kT = 1024, kCout = 256;
constexpr size_t kYBytes     = (size_t)kB * kT * kCout * 4;    // 64 MiB y buffer
constexpr size_t kWfragBytes = (size_t)32 * 8 * 2 * 64 * 16;   // 512 KiB [kc][osub][plane][lane][16B]
constexpr size_t kSBytes     = kCout * 4;
constexpr size_t kWsNeed     = kYBytes + kWfragBytes + kSBytes;
}

// ---- prep: W' = 32*W split into 2 f16 planes (low plane scaled 2^11), A-frag order ----
// A-frag (32x32x16): m(o) = lane&31, k = (lane>>5)*8 + j.  Block (0,0,0) also fills sarr.
__global__ void wsplit16_kernel(const float* __restrict__ W, const float* __restrict__ gamma,
                                const float* __restrict__ rvar,
                                f16* __restrict__ wfrag, float* __restrict__ sarr) {
    const int kc = blockIdx.x, osub = blockIdx.y, p = blockIdx.z;
    const int lane = threadIdx.x;
    const int o  = osub * 32 + (lane & 31);
    const int kb = kc * 16 + (lane >> 5) * 8;
    f16v8 frag;
#pragma unroll
    for (int j = 0; j < 8; ++j) {
        const float w = 32.0f * W[o * kCin + kb + j];   // 2^5 pre-scale (denorm guard)
        const f16 h = (f16)w;                           // RNE
        const float r = w - (float)h;                   // exact
        const f16 l = (f16)(r * 2048.0f);               // low plane scaled 2^11
        frag[j] = p ? l : h;
    }
    *reinterpret_cast<f16v8*>(wfrag + ((size_t)((kc * 8 + osub) * 2 + p) * 64 + lane) * 8) = frag;
    if (kc == 0 && osub == 0 && p == 0) {
#pragma unroll
        for (int j = 0; j < 4; ++j) {
            const int oo = j * 64 + lane;
            sarr[oo] = (float)((double)gamma[oo] / sqrt((double)rvar[oo] + 1e-5));
        }
    }
}

// ---- GEMM: f16 2-plane MFMA, conflict-free LDS B-staging, 1 barrier/chunk ----
// Grid (16 t-chunks, 64 b), 256 threads = 4 waves. Block tile 256o x 64t.
// Wave w: compute o-range w*64..w*64+63 (2 osub), full 64t (2 tsub) -> 12 MFMA/chunk.
// Staging: thread (t = tid&63, kpp = tid>>6) handles k = 4*kpp..4*kpp+3.
// LDS B rows: stride 20 dwords, slot s = 2*plane + q stored at s ^ ((t>>3)&3).
__global__ __launch_bounds__(256, 2)
void gemm_f16_kernel(const float* __restrict__ x, const f16* __restrict__ wfrag,
                     const float* __restrict__ sarr, const float* __restrict__ rmean,
                     const float* __restrict__ beta, float* __restrict__ y) {
    __shared__ union {
        unsigned int Bd[2][64 * 20];   // [buf][t*20 + 4*slot' + dword], 10 KiB
        float        tb[4][32 * 36];   // per-wave epilogue transpose, 18 KiB
    } sh;

    const int tid  = threadIdx.x;
    const int lane = tid & 63;
    const int wave = tid >> 6;          // = wo (compute) = kpp (staging)
    const int n = lane & 31, q = lane >> 5;
    const int b   = blockIdx.y;
    const int tg0 = blockIdx.x * 64;
    const float* __restrict__ xb = x + ((size_t)b << 19);   // b*512*1024
    const f16v8* __restrict__ wf = reinterpret_cast<const f16v8*>(wfrag);

    const int st_t = tid & 63;
    const int kpp  = wave;              // k-quad index 0..3 (k = 4*kpp..4*kpp+3)
    const int st_sw = (st_t >> 3) & 3;
    const int wr_base = 20 * st_t + 2 * (kpp & 1);
    const int s0 = ((0 + (kpp >> 1)) ^ st_sw) * 4;   // plane0 slot offset (dwords)
    const int s1 = ((2 + (kpp >> 1)) ^ st_sw) * 4;   // plane1 slot offset

    f32x16 accA[2][2] = {};   // [osub][tsub] hh
    f32x16 accB[2][2] = {};   // [osub][tsub] cross (scaled 2^11)
    f16v8  af[2][2][2];       // [buf][osub][plane]
    float  xr[2][4];          // [buf][r] fp32 staging

    auto loadX = [&](int kc, float (&xd)[4]) {
        const float* px = xb + (size_t)(kc * 16 + 4 * kpp) * kT + tg0 + st_t;
#pragma unroll
        for (int r = 0; r < 4; ++r) xd[r] = px[(size_t)r * kT];
    };
    auto loadA = [&](int kc, f16v8 (&ad)[2][2]) {
#pragma unroll
        for (int i = 0; i < 2; ++i)
#pragma unroll
            for (int p = 0; p < 2; ++p)
                ad[i][p] = wf[(size_t)((kc * 8 + wave * 2 + i) * 2 + p) * 64 + lane];
    };
    auto stage = [&](int buf, const float (&xd)[4]) {
        auto h01 = __builtin_amdgcn_cvt_pkrtz(xd[0], xd[1]);   // RTZ pack
        auto h23 = __builtin_amdgcn_cvt_pkrtz(xd[2], xd[3]);
        auto l01 = __builtin_amdgcn_cvt_pkrtz((xd[0] - (float)h01[0]) * 2048.0f,
                                              (xd[1] - (float)h01[1]) * 2048.0f);
        auto l23 = __builtin_amdgcn_cvt_pkrtz((xd[2] - (float)h23[0]) * 2048.0f,
                                              (xd[3] - (float)h23[1]) * 2048.0f);
        h16v4 hv, lv;
        hv[0] = h01[0]; hv[1] = h01[1]; hv[2] = h23[0]; hv[3] = h23[1];
        lv[0] = l01[0]; lv[1] = l01[1]; lv[2] = l23[0]; lv[3] = l23[1];
        *reinterpret_cast<h16v4*>(&sh.Bd[buf][wr_base + s0]) = hv;   // ds_write_b64, 2-way free
        *reinterpret_cast<h16v4*>(&sh.Bd[buf][wr_base + s1]) = lv;
    };
    auto domfma = [&](int buf, const f16v8 (&ad)[2][2]) {
#pragma unroll
        for (int s = 0; s < 2; ++s) {
            const int t = s * 32 + n;
            const int sw = (t >> 3) & 3;
            const f16v8 bh = *reinterpret_cast<const f16v8*>(&sh.Bd[buf][20 * t + 4 * ((0 + q) ^ sw)]);
            const f16v8 bl = *reinterpret_cast<const f16v8*>(&sh.Bd[buf][20 * t + 4 * ((2 + q) ^ sw)]);
#pragma unroll
            for (int i = 0; i < 2; ++i) {
                accA[i][s] = __builtin_amdgcn_mfma_f32_32x32x16_f16(ad[i][0], bh, accA[i][s], 0, 0, 0);
                accB[i][s] = __builtin_amdgcn_mfma_f32_32x32x16_f16(ad[i][0], bl, accB[i][s], 0, 0, 0);
                accB[i][s] = __builtin_amdgcn_mfma_f32_32x32x16_f16(ad[i][1], bh, accB[i][s], 0, 0, 0);
            }
        }
    };

    // prologue
    loadX(0, xr[0]);
    loadA(0, af[0]);
    stage(0, xr[0]);
    loadX(1, xr[1]);
    __syncthreads();

#pragma unroll 2
    for (int kc = 0; kc < 32; ++kc) {
        const int cur = kc & 1, nxt = cur ^ 1;
        if (kc < 31) loadA(kc + 1, af[nxt]);
        if (kc < 31) stage(nxt, xr[nxt]);   // x of chunk kc+1
        if (kc < 30) loadX(kc + 2, xr[cur]);
        domfma(cur, af[cur]);
        __syncthreads();
    }

    // ---- epilogue: combine planes, per-wave LDS transpose, BN affine, store y[b][t][o] ----
    float* tb = sh.tb[wave];
#pragma unroll
    for (int i = 0; i < 2; ++i)
#pragma unroll
        for (int s = 0; s < 2; ++s) {
            const f32x16 v = accA[i][s] + accB[i][s] * 4.8828125e-4f;   // + cross/2^11
            asm volatile("s_waitcnt lgkmcnt(0)" ::: "memory");
#pragma unroll
            for (int g = 0; g < 4; ++g) {
                f32x4 t4;
                t4.x = v[4 * g + 0]; t4.y = v[4 * g + 1];
                t4.z = v[4 * g + 2]; t4.w = v[4 * g + 3];
                // C/D: col(t)=lane&31, row(o)=(reg&3)+8*(reg>>2)+4*(lane>>5)
                *reinterpret_cast<f32x4*>(tb + n * 36 + g * 8 + q * 4) = t4;
            }
            asm volatile("s_waitcnt lgkmcnt(0)" ::: "memory");
#pragma unroll
            for (int r4 = 0; r4 < 4; ++r4) {
                const int fidx = lane + 64 * r4;
                const int tl = fidx >> 3, o4 = fidx & 7;
                const int og = wave * 64 + i * 32 + o4 * 4;
                f32x4 val = *reinterpret_cast<const f32x4*>(tb + tl * 36 + o4 * 4);
                const f32x4 sv = *reinterpret_cast<const f32x4*>(sarr + og);
                const f32x4 mv = *reinterpret_cast<const f32x4*>(rmean + og);
                const f32x4 bv = *reinterpret_cast<const f32x4*>(beta + og);
                val = (val * 0.03125f - mv) * sv + bv;   // exact /32 un-scale, then BN
                const size_t t = (size_t)tg0 + s * 32 + tl;
                *reinterpret_cast<f32x4*>(y + ((((size_t)b << 10) + t) << 8) + og) = val;
            }
        }
}

// ---- LIF: one wave per (b, 64-o slice), deep load pipelining ----
__global__ __launch_bounds__(64)
void lif_kernel(const float* __restrict__ y, float* __restrict__ out) {
    const int b = blockIdx.x >> 2;
    const int o = ((blockIdx.x & 3) << 6) + threadIdx.x;
    const float* __restrict__ yb = y + ((size_t)b << 18);
    float v = 0.f;
    int cnt = 0;
    float b0[32], b1[32];
    auto loadb = [&](int i, float (&buf)[32]) {
#pragma unroll
        for (int j = 0; j < 32; ++j)
            buf[j] = yb[(size_t)(i * 32 + j) * 256 + o];
    };
    auto stepb = [&](const float (&buf)[32]) {
#pragma unroll
        for (int j = 0; j < 32; ++j) {
            v = v + (buf[j] - v) * 0.5f;
            if (v - 1.0f >= 0.0f) { ++cnt; v = 0.f; }
        }
    };
    loadb(0, b0);
    for (int bb = 0; bb < 16; ++bb) {
        loadb(2 * bb + 1, b1);
        stepb(b0);
        if (bb < 15) loadb(2 * bb + 2, b0);
        stepb(b1);
    }
    out[((size_t)b << 8) + o] = (float)cnt * (1.0f / 1024.0f);
}

// ---- fallback (round-1 fp32 fused path, unchanged) ----
namespace fb {
constexpr int kOTile = 32, kTTile = 128, kCc = 64;
constexpr int kNtt = kT / kTTile, kNcc = kCin / kCc, kYPad = 132;
}

__global__ void wt_transpose_kernel(const float* __restrict__ W, float* __restrict__ Wt) {
    int idx = blockIdx.x * 256 + threadIdx.x;
    int c = idx >> 8, o = idx & 255;
    Wt[idx] = W[o * kCin + c];
}

__global__ __launch_bounds__(256, 2)
void snn_fused_kernel(const float* __restrict__ x, const float* __restrict__ Wt,
                      const float* __restrict__ gamma, const float* __restrict__ beta,
                      const float* __restrict__ rmean, const float* __restrict__ rvar,
                      float* __restrict__ out) {
    using namespace fb;
    __shared__ float xs[kCc][kTTile];
    __shared__ float ws[kCc][kOTile];
    __shared__ float ytile[kOTile][kYPad];
    __shared__ float sarr[kOTile], barr[kOTile], marr[kOTile], vstate[kOTile];
    __shared__ int scnt[kOTile];
    const int tid = threadIdx.x, tx = tid & 31, ty = tid >> 5;
    const int b = blockIdx.y, o_blk = blockIdx.x * kOTile;
    if (tid < kOTile) {
        const int o = o_blk + tid;
        const double dinv = 1.0 / sqrt((double)rvar[o] + 1e-5);
        sarr[tid] = (float)(dinv * (double)gamma[o]);
        barr[tid] = beta[o]; marr[tid] = rmean[o];
        vstate[tid] = 0.0f; scnt[tid] = 0;
    }
    __syncthreads();
    const float* xb = x + (size_t)b * kCin * kT;
    for (int tt = 0; tt < kNtt; ++tt) {
        float acc[4][4];
#pragma unroll
        for (int i = 0; i < 4; ++i)
#pragma unroll
            for (int j = 0; j < 4; ++j) acc[i][j] = 0.0f;
        const int t0 = tt * kTTile;
        for (int cc = 0; cc < kNcc; ++cc) {
#pragma unroll
            for (int k = 0; k < 8; ++k) {
                const int f = tid + 256 * k;
                const int c = f >> 5, tq = f & 31;
                *reinterpret_cast<float4*>(&xs[c][tq * 4]) = *reinterpret_cast<const float4*>(
                    xb + (size_t)(cc * kCc + c) * kT + t0 + tq * 4);
            }
#pragma unroll
            for (int k = 0; k < 2; ++k) {
                const int f = tid + 256 * k;
                const int c = f >> 3, oq = f & 7;
                *reinterpret_cast<float4*>(&ws[c][oq * 4]) = *reinterpret_cast<const float4*>(
                    Wt + (size_t)(cc * kCc + c) * kCout + o_blk + oq * 4);
            }
            __syncthreads();
#pragma unroll 8
            for (int c = 0; c < kCc; ++c) {
                const float4 xv = *reinterpret_cast<const float4*>(&xs[c][tx * 4]);
                const float4 wv = *reinterpret_cast<const float4*>(&ws[c][ty * 4]);
                const float xf[4] = {xv.x, xv.y, xv.z, xv.w};
                const float wf4[4] = {wv.x, wv.y, wv.z, wv.w};
#pragma unroll
                for (int i = 0; i < 4; ++i)
#pragma unroll
                    for (int j = 0; j < 4; ++j) acc[i][j] += wf4[i] * xf[j];
            }
            __syncthreads();
        }
#pragma unroll
        for (int i = 0; i < 4; ++i) {
            const int o = ty * 4 + i;
            const float s = sarr[o], bb2 = barr[o], m = marr[o];
#pragma unroll
            for (int j = 0; j < 4; ++j) ytile[o][tx * 4 + j] = (acc[i][j] - m) * s + bb2;
        }
        __syncthreads();
        if (tid < kOTile) {
            float vv = vstate[tid];
            int cnt = 0;
#pragma unroll 4
            for (int t = 0; t < kTTile; ++t) {
                const float yv = ytile[tid][t];
                vv = vv + (yv - vv) * 0.5f;
                if (vv - 1.0f >= 0.0f) { cnt++; vv = 0.0f; }
            }
            vstate[tid] = vv; scnt[tid] += cnt;
        }
        __syncthreads();
    }
    if (tid < kOTile) out[b * kCout + o_blk + tid] = (float)scnt[tid] * (1.0f / 1024.0f);
}

extern "C" void kernel_launch(void* const* d_in, const int* in_sizes, int n_in,
                              void* d_out, int out_size, void* d_ws, size_t ws_size,
                              hipStream_t stream) {
    const float* x     = (const float*)d_in[0];
    const float* W     = (const float*)d_in[1];
    const float* gamma = (const float*)d_in[2];
    const float* beta  = (const float*)d_in[3];
    const float* rmean = (const float*)d_in[4];
    const float* rvar  = (const float*)d_in[5];
    float* out = (float*)d_out;

    if (ws_size >= kWsNeed) {
        float* y     = (float*)d_ws;
        f16*   wfrag = (f16*)((char*)d_ws + kYBytes);
        float* sarr  = (float*)((char*)d_ws + kYBytes + kWfragBytes);
        wsplit16_kernel<<<dim3(32, 8, 2), 64, 0, stream>>>(W, gamma, rvar, wfrag, sarr);
        gemm_f16_kernel<<<dim3(16, 64), 256, 0, stream>>>(x, wfrag, sarr, rmean, beta, y);
        lif_kernel<<<256, 64, 0, stream>>>(y, out);
    } else {
        float* Wt = (float*)d_ws;
        wt_transpose_kernel<<<(kCin * kCout) / 256, 256, 0, stream>>>(W, Wt);
        snn_fused_kernel<<<dim3(kCout / fb::kOTile, kB), 256, 0, stream>>>(
            x, Wt, gamma, beta, rmean, rvar, out);
    }
}

// Round 6
// 254.223 us; speedup vs baseline: 1.7235x; 1.0078x over previous
//
#include <hip/hip_runtime.h>
#include <math.h>

typedef _Float16 f16;
typedef __attribute__((ext_vector_type(8)))  _Float16 f16v8;
typedef __attribute__((ext_vector_type(4)))  __fp16   h16v4;
typedef __attribute__((ext_vector_type(16))) float    f32x16;
typedef __attribute__((ext_vector_type(4)))  float    f32x4;

namespace {
constexpr int kB = 64, kCin = 512, kT = 1024, kCout = 256;
constexpr size_t kYBytes     = (size_t)kB * kT * kCout * 4;    // 64 MiB y buffer
constexpr size_t kWfragBytes = (size_t)32 * 8 * 2 * 64 * 16;   // 512 KiB [kc][osub][plane][lane][16B]
constexpr size_t kSBytes     = kCout * 4;
constexpr size_t kWsNeed     = kYBytes + kWfragBytes + kSBytes;
}

// ---- prep: W' = 32*W split into 2 f16 planes (low plane scaled 2^11), A-frag order ----
// A-frag (32x32x16): m(o) = lane&31, k = (lane>>5)*8 + j.  Block (0,0,0) also fills sarr.
__global__ void wsplit16_kernel(const float* __restrict__ W, const float* __restrict__ gamma,
                                const float* __restrict__ rvar,
                                f16* __restrict__ wfrag, float* __restrict__ sarr) {
    const int kc = blockIdx.x, osub = blockIdx.y, p = blockIdx.z;
    const int lane = threadIdx.x;
    const int o  = osub * 32 + (lane & 31);
    const int kb = kc * 16 + (lane >> 5) * 8;
    f16v8 frag;
#pragma unroll
    for (int j = 0; j < 8; ++j) {
        const float w = 32.0f * W[o * kCin + kb + j];   // 2^5 pre-scale (denorm guard)
        const f16 h = (f16)w;                           // RNE
        const float r = w - (float)h;                   // exact
        const f16 l = (f16)(r * 2048.0f);               // low plane scaled 2^11
        frag[j] = p ? l : h;
    }
    *reinterpret_cast<f16v8*>(wfrag + ((size_t)((kc * 8 + osub) * 2 + p) * 64 + lane) * 8) = frag;
    if (kc == 0 && osub == 0 && p == 0) {
#pragma unroll
        for (int j = 0; j < 4; ++j) {
            const int oo = j * 64 + lane;
            sarr[oo] = (float)((double)gamma[oo] / sqrt((double)rvar[oo] + 1e-5));
        }
    }
}

// ---- GEMM: f16 2-plane MFMA, 4-deep x prefetch, lgkm-only barriers ----
// Grid (16 t-chunks, 64 b), 256 threads = 4 waves. Block tile 256o x 64t.
// Wave w computes o-range w*64.. (2 osub) x 64t (2 tsub) -> 12 MFMA/chunk.
// Barrier = s_waitcnt lgkmcnt(0) + s_barrier ONLY: global x/A loads stay in
// flight across barriers (prefetch distance 3 chunks > HBM latency).
__global__ __launch_bounds__(256, 2)
void gemm_f16_kernel(const float* __restrict__ x, const f16* __restrict__ wfrag,
                     const float* __restrict__ sarr, const float* __restrict__ rmean,
                     const float* __restrict__ beta, float* __restrict__ y) {
    __shared__ union {
        unsigned int Bd[2][64 * 20];   // [buf][t*20 + 4*slot' + dword], 10 KiB
        float        tb[4][32 * 36];   // per-wave epilogue transpose, 18 KiB
    } sh;

    const int tid  = threadIdx.x;
    const int lane = tid & 63;
    const int wave = tid >> 6;          // = wo (compute) = kpp (staging)
    const int n = lane & 31, q = lane >> 5;
    const int b   = blockIdx.y;
    const int tg0 = blockIdx.x * 64;
    const float* __restrict__ xb = x + ((size_t)b << 19);   // b*512*1024
    const f16v8* __restrict__ wf = reinterpret_cast<const f16v8*>(wfrag);

    const int st_t = tid & 63;
    const int kpp  = wave;              // k-quad index 0..3 (k = 4*kpp..4*kpp+3)
    const int st_sw = (st_t >> 3) & 3;
    const int wr_base = 20 * st_t + 2 * (kpp & 1);
    const int s0 = ((0 + (kpp >> 1)) ^ st_sw) * 4;   // plane0 slot offset (dwords)
    const int s1 = ((2 + (kpp >> 1)) ^ st_sw) * 4;   // plane1 slot offset

    f32x16 accA[2][2] = {};   // [osub][tsub] hh
    f32x16 accB[2][2] = {};   // [osub][tsub] cross (scaled 2^11)
    f16v8  af[2][2][2];       // [buf][osub][plane]
    float  xq[4][4];          // [slot][r] 4-deep x prefetch queue

    auto loadX = [&](int kc, float (&xd)[4]) {
        const float* px = xb + (size_t)(kc * 16 + 4 * kpp) * kT + tg0 + st_t;
#pragma unroll
        for (int r = 0; r < 4; ++r) xd[r] = px[(size_t)r * kT];
    };
    auto loadA = [&](int kc, f16v8 (&ad)[2][2]) {
#pragma unroll
        for (int i = 0; i < 2; ++i)
#pragma unroll
            for (int p = 0; p < 2; ++p)
                ad[i][p] = wf[(size_t)((kc * 8 + wave * 2 + i) * 2 + p) * 64 + lane];
    };
    auto stage = [&](int buf, const float (&xd)[4]) {
        auto h01 = __builtin_amdgcn_cvt_pkrtz(xd[0], xd[1]);   // RTZ pack
        auto h23 = __builtin_amdgcn_cvt_pkrtz(xd[2], xd[3]);
        auto l01 = __builtin_amdgcn_cvt_pkrtz((xd[0] - (float)h01[0]) * 2048.0f,
                                              (xd[1] - (float)h01[1]) * 2048.0f);
        auto l23 = __builtin_amdgcn_cvt_pkrtz((xd[2] - (float)h23[0]) * 2048.0f,
                                              (xd[3] - (float)h23[1]) * 2048.0f);
        h16v4 hv, lv;
        hv[0] = h01[0]; hv[1] = h01[1]; hv[2] = h23[0]; hv[3] = h23[1];
        lv[0] = l01[0]; lv[1] = l01[1]; lv[2] = l23[0]; lv[3] = l23[1];
        *reinterpret_cast<h16v4*>(&sh.Bd[buf][wr_base + s0]) = hv;   // ds_write_b64
        *reinterpret_cast<h16v4*>(&sh.Bd[buf][wr_base + s1]) = lv;
    };
    auto domfma = [&](int buf, const f16v8 (&ad)[2][2]) {
#pragma unroll
        for (int s = 0; s < 2; ++s) {
            const int t = s * 32 + n;
            const int sw = (t >> 3) & 3;
            const f16v8 bh = *reinterpret_cast<const f16v8*>(&sh.Bd[buf][20 * t + 4 * ((0 + q) ^ sw)]);
            const f16v8 bl = *reinterpret_cast<const f16v8*>(&sh.Bd[buf][20 * t + 4 * ((2 + q) ^ sw)]);
#pragma unroll
            for (int i = 0; i < 2; ++i) {
                accA[i][s] = __builtin_amdgcn_mfma_f32_32x32x16_f16(ad[i][0], bh, accA[i][s], 0, 0, 0);
                accB[i][s] = __builtin_amdgcn_mfma_f32_32x32x16_f16(ad[i][0], bl, accB[i][s], 0, 0, 0);
                accB[i][s] = __builtin_amdgcn_mfma_f32_32x32x16_f16(ad[i][1], bh, accB[i][s], 0, 0, 0);
            }
        }
    };

    // prologue: fill 4-deep x queue, A buf 0, stage chunk 0
    loadX(0, xq[0]); loadX(1, xq[1]); loadX(2, xq[2]); loadX(3, xq[3]);
    loadA(0, af[0]);
    stage(0, xq[0]);
    asm volatile("s_waitcnt lgkmcnt(0)\n\ts_barrier" ::: "memory");

    for (int kc4 = 0; kc4 < 8; ++kc4) {
#pragma unroll
        for (int u = 0; u < 4; ++u) {
            const int kc = kc4 * 4 + u;
            const int cur = kc & 1, nxt = cur ^ 1;
            if (kc < 31) loadA(kc + 1, af[nxt]);
            if (kc < 31) stage(nxt, xq[(u + 1) & 3]);   // x of chunk kc+1
            if (kc < 28) loadX(kc + 4, xq[u]);          // refill slot (distance 3)
            domfma(cur, af[cur]);
            // lgkm-only barrier: LDS writes visible, global loads stay in flight
            asm volatile("s_waitcnt lgkmcnt(0)\n\ts_barrier" ::: "memory");
        }
    }

    // ---- epilogue: combine planes, per-wave LDS transpose, BN affine, store y[b][t][o] ----
    float* tb = sh.tb[wave];
#pragma unroll
    for (int i = 0; i < 2; ++i)
#pragma unroll
        for (int s = 0; s < 2; ++s) {
            const f32x16 v = accA[i][s] + accB[i][s] * 4.8828125e-4f;   // + cross/2^11
            asm volatile("s_waitcnt lgkmcnt(0)" ::: "memory");
#pragma unroll
            for (int g = 0; g < 4; ++g) {
                f32x4 t4;
                t4.x = v[4 * g + 0]; t4.y = v[4 * g + 1];
                t4.z = v[4 * g + 2]; t4.w = v[4 * g + 3];
                // C/D: col(t)=lane&31, row(o)=(reg&3)+8*(reg>>2)+4*(lane>>5)
                *reinterpret_cast<f32x4*>(tb + n * 36 + g * 8 + q * 4) = t4;
            }
            asm volatile("s_waitcnt lgkmcnt(0)" ::: "memory");
#pragma unroll
            for (int r4 = 0; r4 < 4; ++r4) {
                const int fidx = lane + 64 * r4;
                const int tl = fidx >> 3, o4 = fidx & 7;
                const int og = wave * 64 + i * 32 + o4 * 4;
                f32x4 val = *reinterpret_cast<const f32x4*>(tb + tl * 36 + o4 * 4);
                const f32x4 sv = *reinterpret_cast<const f32x4*>(sarr + og);
                const f32x4 mv = *reinterpret_cast<const f32x4*>(rmean + og);
                const f32x4 bv = *reinterpret_cast<const f32x4*>(beta + og);
                val = (val * 0.03125f - mv) * sv + bv;   // exact /32 un-scale, then BN
                const size_t t = (size_t)tg0 + s * 32 + tl;
                *reinterpret_cast<f32x4*>(y + ((((size_t)b << 10) + t) << 8) + og) = val;
            }
        }
}

// ---- LIF: one wave per (b, 64-o slice), 4-deep batch prefetch ----
__global__ __launch_bounds__(64)
void lif_kernel(const float* __restrict__ y, float* __restrict__ out) {
    const int b = blockIdx.x >> 2;
    const int o = ((blockIdx.x & 3) << 6) + threadIdx.x;
    const float* __restrict__ yb = y + ((size_t)b << 18);
    float v = 0.f;
    int cnt = 0;
    float buf[4][32];
    auto loadb = [&](int i, float (&bf)[32]) {
#pragma unroll
        for (int j = 0; j < 32; ++j)
            bf[j] = yb[(size_t)(i * 32 + j) * 256 + o];
    };
    auto stepb = [&](const float (&bf)[32]) {
#pragma unroll
        for (int j = 0; j < 32; ++j) {
            v = v + (bf[j] - v) * 0.5f;             // bit-exact reference recurrence
            if (v - 1.0f >= 0.0f) { ++cnt; v = 0.f; }
        }
    };
    loadb(0, buf[0]); loadb(1, buf[1]); loadb(2, buf[2]);
    for (int i4 = 0; i4 < 8; ++i4) {
#pragma unroll
        for (int u = 0; u < 4; ++u) {
            const int i = i4 * 4 + u;
            if (i < 29) loadb(i + 3, buf[(u + 3) & 3]);   // distance-3 prefetch
            stepb(buf[u]);
        }
    }
    out[((size_t)b << 8) + o] = (float)cnt * (1.0f / 1024.0f);
}

// ---- fallback (round-1 fp32 fused path, unchanged) ----
namespace fb {
constexpr int kOTile = 32, kTTile = 128, kCc = 64;
constexpr int kNtt = kT / kTTile, kNcc = kCin / kCc, kYPad = 132;
}

__global__ void wt_transpose_kernel(const float* __restrict__ W, float* __restrict__ Wt) {
    int idx = blockIdx.x * 256 + threadIdx.x;
    int c = idx >> 8, o = idx & 255;
    Wt[idx] = W[o * kCin + c];
}

__global__ __launch_bounds__(256, 2)
void snn_fused_kernel(const float* __restrict__ x, const float* __restrict__ Wt,
                      const float* __restrict__ gamma, const float* __restrict__ beta,
                      const float* __restrict__ rmean, const float* __restrict__ rvar,
                      float* __restrict__ out) {
    using namespace fb;
    __shared__ float xs[kCc][kTTile];
    __shared__ float ws[kCc][kOTile];
    __shared__ float ytile[kOTile][kYPad];
    __shared__ float sarr[kOTile], barr[kOTile], marr[kOTile], vstate[kOTile];
    __shared__ int scnt[kOTile];
    const int tid = threadIdx.x, tx = tid & 31, ty = tid >> 5;
    const int b = blockIdx.y, o_blk = blockIdx.x * kOTile;
    if (tid < kOTile) {
        const int o = o_blk + tid;
        const double dinv = 1.0 / sqrt((double)rvar[o] + 1e-5);
        sarr[tid] = (float)(dinv * (double)gamma[o]);
        barr[tid] = beta[o]; marr[tid] = rmean[o];
        vstate[tid] = 0.0f; scnt[tid] = 0;
    }
    __syncthreads();
    const float* xb = x + (size_t)b * kCin * kT;
    for (int tt = 0; tt < kNtt; ++tt) {
        float acc[4][4];
#pragma unroll
        for (int i = 0; i < 4; ++i)
#pragma unroll
            for (int j = 0; j < 4; ++j) acc[i][j] = 0.0f;
        const int t0 = tt * kTTile;
        for (int cc = 0; cc < kNcc; ++cc) {
#pragma unroll
            for (int k = 0; k < 8; ++k) {
                const int f = tid + 256 * k;
                const int c = f >> 5, tq = f & 31;
                *reinterpret_cast<float4*>(&xs[c][tq * 4]) = *reinterpret_cast<const float4*>(
                    xb + (size_t)(cc * kCc + c) * kT + t0 + tq * 4);
            }
#pragma unroll
            for (int k = 0; k < 2; ++k) {
                const int f = tid + 256 * k;
                const int c = f >> 3, oq = f & 7;
                *reinterpret_cast<float4*>(&ws[c][oq * 4]) = *reinterpret_cast<const float4*>(
                    Wt + (size_t)(cc * kCc + c) * kCout + o_blk + oq * 4);
            }
            __syncthreads();
#pragma unroll 8
            for (int c = 0; c < kCc; ++c) {
                const float4 xv = *reinterpret_cast<const float4*>(&xs[c][tx * 4]);
                const float4 wv = *reinterpret_cast<const float4*>(&ws[c][ty * 4]);
                const float xf[4] = {xv.x, xv.y, xv.z, xv.w};
                const float wf4[4] = {wv.x, wv.y, wv.z, wv.w};
#pragma unroll
                for (int i = 0; i < 4; ++i)
#pragma unroll
                    for (int j = 0; j < 4; ++j) acc[i][j] += wf4[i] * xf[j];
            }
            __syncthreads();
        }
#pragma unroll
        for (int i = 0; i < 4; ++i) {
            const int o = ty * 4 + i;
            const float s = sarr[o], bb2 = barr[o], m = marr[o];
#pragma unroll
            for (int j = 0; j < 4; ++j) ytile[o][tx * 4 + j] = (acc[i][j] - m) * s + bb2;
        }
        __syncthreads();
        if (tid < kOTile) {
            float vv = vstate[tid];
            int cnt = 0;
#pragma unroll 4
            for (int t = 0; t < kTTile; ++t) {
                const float yv = ytile[tid][t];
                vv = vv + (yv - vv) * 0.5f;
                if (vv - 1.0f >= 0.0f) { cnt++; vv = 0.0f; }
            }
            vstate[tid] = vv; scnt[tid] += cnt;
        }
        __syncthreads();
    }
    if (tid < kOTile) out[b * kCout + o_blk + tid] = (float)scnt[tid] * (1.0f / 1024.0f);
}

extern "C" void kernel_launch(void* const* d_in, const int* in_sizes, int n_in,
                              void* d_out, int out_size, void* d_ws, size_t ws_size,
                              hipStream_t stream) {
    const float* x     = (const float*)d_in[0];
    const float* W     = (const float*)d_in[1];
    const float* gamma = (const float*)d_in[2];
    const float* beta  = (const float*)d_in[3];
    const float* rmean = (const float*)d_in[4];
    const float* rvar  = (const float*)d_in[5];
    float* out = (float*)d_out;

    if (ws_size >= kWsNeed) {
        float* y     = (float*)d_ws;
        f16*   wfrag = (f16*)((char*)d_ws + kYBytes);
        float* sarr  = (float*)((char*)d_ws + kYBytes + kWfragBytes);
        wsplit16_kernel<<<dim3(32, 8, 2), 64, 0, stream>>>(W, gamma, rvar, wfrag, sarr);
        gemm_f16_kernel<<<dim3(16, 64), 256, 0, stream>>>(x, wfrag, sarr, rmean, beta, y);
        lif_kernel<<<256, 64, 0, stream>>>(y, out);
    } else {
        float* Wt = (float*)d_ws;
        wt_transpose_kernel<<<(kCin * kCout) / 256, 256, 0, stream>>>(W, Wt);
        snn_fused_kernel<<<dim3(kCout / fb::kOTile, kB), 256, 0, stream>>>(
            x, Wt, gamma, beta, rmean, rvar, out);
    }
}